// Round 3
// baseline (243.118 us; speedup 1.0000x reference)
//
#include <hip/hip_runtime.h>

// Problem constants (fixed by the reference)
#define BATCH   262144
#define DDIM    128
#define GRID    2048
#define NITER   8            // BATCH / (GRID * 4 waves * 2 rows * ... ) exact tiling
// blocks: j%3==0 dense, j%3==1 diagonal, j%3==2 lowrank; k = j/3.

typedef float v2f __attribute__((ext_vector_type(2)));
typedef float v4f __attribute__((ext_vector_type(4)));

// quad_perm DPP: lane gets value from lane (quad_base | perm[lane&3]).
// xor1 -> [1,0,3,2] = 0xB1 ; xor2 -> [2,3,0,1] = 0x4E ; xor3 -> [3,2,1,0] = 0x1B
template<int CTRL>
__device__ __forceinline__ float qperm(float v) {
    return __int_as_float(__builtin_amdgcn_update_dpp(
        0, __float_as_int(v), CTRL, 0xF, 0xF, true));
}
// ds_swizzle BitMode: offset = (xor<<10) | 0x1F  (within 32-lane groups)
template<int PAT>
__device__ __forceinline__ float swz(float v) {
    return __int_as_float(__builtin_amdgcn_ds_swizzle(__float_as_int(v), PAT));
}

__global__ __launch_bounds__(256, 3) void bdla_kernel(
    const float* __restrict__ x,
    const float* __restrict__ Wd,   // [3,16,16]  W[k][o][d]
    const float* __restrict__ sd,   // [3,16]
    const float* __restrict__ U,    // [2,16,4]
    const float* __restrict__ V,    // [2,16,4]
    float* __restrict__ out)
{
    __shared__ float lds[1072];     // 768 Wd | 48 sd | 128 U | 128 V
    const int tid = threadIdx.x;
    for (int i = tid; i < 768; i += 256) lds[i] = Wd[i];
    if (tid < 48)  lds[768 + tid] = sd[tid];
    if (tid < 128) lds[816 + tid] = U[tid];
    if (tid < 128) lds[944 + tid] = V[tid];
    __syncthreads();

    const int lane   = tid & 63;
    const int lane32 = lane & 31;
    const int half   = lane >> 5;      // which row of the wave's pair
    const int j      = lane32 >> 2;    // block id 0..7
    const int sub    = lane32 & 3;     // quarter within block (4 outputs)
    const int mode   = j % 3;          // 0 dense, 1 diag, 2 lowrank
    const int k      = j / 3;

    // A[oo][m*4+c]: weight applied to g[m*4+c] = qperm<xor m>(xv[c]),
    // i.e. block-input element d = (sub^m)*4 + c.
    float A[4][16];
    if (mode == 0) {
        const float* w = &lds[k * 256];
#pragma unroll
        for (int oo = 0; oo < 4; ++oo) {
            const int o = sub * 4 + oo;
#pragma unroll
            for (int m = 0; m < 4; ++m)
#pragma unroll
                for (int c = 0; c < 4; ++c)
                    A[oo][m * 4 + c] = w[o * 16 + ((sub ^ m) * 4 + c)];
        }
    } else if (mode == 1) {
        const float* s = &lds[768 + k * 16];
#pragma unroll
        for (int oo = 0; oo < 4; ++oo)
#pragma unroll
            for (int m = 0; m < 4; ++m)
#pragma unroll
                for (int c = 0; c < 4; ++c)
                    A[oo][m * 4 + c] = (m == 0 && c == oo) ? s[sub * 4 + oo] : 0.0f;
    } else {
        const float* u = &lds[816 + k * 64];
        const float* v = &lds[944 + k * 64];
#pragma unroll
        for (int oo = 0; oo < 4; ++oo) {
            const int o = sub * 4 + oo;
#pragma unroll
            for (int m = 0; m < 4; ++m)
#pragma unroll
                for (int c = 0; c < 4; ++c) {
                    const int d = (sub ^ m) * 4 + c;
                    float acc = 0.0f;
#pragma unroll
                    for (int r = 0; r < 4; ++r)
                        acc += u[o * 4 + r] * v[d * 4 + r];
                    A[oo][m * 4 + c] = acc;
                }
        }
    }

    // Pin A into VGPRs (R1 lesson: without this the compiler remats A from
    // LDS inside the hot loop).
#pragma unroll
    for (int oo = 0; oo < 4; ++oo)
#pragma unroll
        for (int t = 0; t < 16; ++t)
            asm volatile("" : "+v"(A[oo][t]));

    // Pack for v_pk_fma_f32: pair (row0,row1) and (row2,row3).
    v2f A01[16], A23[16];
#pragma unroll
    for (int t = 0; t < 16; ++t) {
        A01[t] = v2f{A[0][t], A[1][t]};
        A23[t] = v2f{A[2][t], A[3][t]};
    }

    // Row mapping: wave gw, iter it -> rows it*32768 + gw*4 + {half, 2+half}
    const int gw = blockIdx.x * 4 + (tid >> 6);
    const float* xbase = x   + (size_t)(gw * 4 + half) * DDIM + lane32 * 4;
    float*       obase = out + (size_t)(gw * 4 + half) * DDIM + lane32 * 4;
    const size_t istep = (size_t)(GRID * 4 * 4) * DDIM;   // floats per iter step

    // per-row compute: gather via quad_perm DPP (VALU pipe), pk-FMA,
    // norm butterfly = 2 DPP adds + 3 ds_swizzle adds.
    auto rowcompute = [&](v4f r) -> v4f {
        float g[16];
        g[0] = r.x; g[1] = r.y; g[2] = r.z; g[3] = r.w;
        g[4]  = qperm<0xB1>(r.x); g[5]  = qperm<0xB1>(r.y);
        g[6]  = qperm<0xB1>(r.z); g[7]  = qperm<0xB1>(r.w);
        g[8]  = qperm<0x4E>(r.x); g[9]  = qperm<0x4E>(r.y);
        g[10] = qperm<0x4E>(r.z); g[11] = qperm<0x4E>(r.w);
        g[12] = qperm<0x1B>(r.x); g[13] = qperm<0x1B>(r.y);
        g[14] = qperm<0x1B>(r.z); g[15] = qperm<0x1B>(r.w);

        v2f acc01 = v2f{0.f, 0.f}, acc23 = v2f{0.f, 0.f};
#pragma unroll
        for (int t = 0; t < 16; ++t) {
            const v2f gg = v2f{g[t], g[t]};
            acc01 += A01[t] * gg;
            acc23 += A23[t] * gg;
        }

        float ss = acc01.x * acc01.x + acc01.y * acc01.y
                 + acc23.x * acc23.x + acc23.y * acc23.y;
        ss += qperm<0xB1>(ss);      // xor 1 (DPP, VALU pipe)
        ss += qperm<0x4E>(ss);      // xor 2 (DPP, VALU pipe)
        ss += swz<0x101F>(ss);      // xor 4
        ss += swz<0x201F>(ss);      // xor 8
        ss += swz<0x401F>(ss);      // xor 16
        const float inv = 1.0f / (sqrtf(ss) + 1e-8f);

        v4f y;
        y.x = acc01.x * inv; y.y = acc01.y * inv;
        y.z = acc23.x * inv; y.w = acc23.y * inv;
        return y;
    };

    // depth-2 software pipeline
    v4f a0 = *(const v4f*)(xbase);
    v4f b0 = *(const v4f*)(xbase + 2 * DDIM);
    v4f a1 = *(const v4f*)(xbase + istep);
    v4f b1 = *(const v4f*)(xbase + istep + 2 * DDIM);

#pragma unroll
    for (int it = 0; it < NITER; ++it) {
        v4f a2, b2;
        if (it + 2 < NITER) {
            a2 = *(const v4f*)(xbase + (size_t)(it + 2) * istep);
            b2 = *(const v4f*)(xbase + (size_t)(it + 2) * istep + 2 * DDIM);
        }

        const v4f ya = rowcompute(a0);
        const v4f yb = rowcompute(b0);

        // non-temporal: don't let the 134 MB output stream evict x from LLC
        __builtin_nontemporal_store(ya, (v4f*)(obase + (size_t)it * istep));
        __builtin_nontemporal_store(yb, (v4f*)(obase + (size_t)it * istep + 2 * DDIM));

        a0 = a1; b0 = b1; a1 = a2; b1 = b2;
    }
}

extern "C" void kernel_launch(void* const* d_in, const int* in_sizes, int n_in,
                              void* d_out, int out_size, void* d_ws, size_t ws_size,
                              hipStream_t stream) {
    const float* x  = (const float*)d_in[0];
    const float* Wd = (const float*)d_in[1];
    const float* sd = (const float*)d_in[2];
    const float* U  = (const float*)d_in[3];
    const float* V  = (const float*)d_in[4];
    float* out = (float*)d_out;
    (void)in_sizes; (void)n_in; (void)out_size; (void)d_ws; (void)ws_size;

    dim3 grid(GRID), block(256);
    hipLaunchKernelGGL(bdla_kernel, grid, block, 0, stream, x, Wd, sd, U, V, out);
}